// Round 1
// baseline (3251.842 us; speedup 1.0000x reference)
//
#include <hip/hip_runtime.h>
#include <math.h>

#define FB 512
#define TB 256
#define PLANE (FB * TB)   // 131072 floats per (b,c,d) plane
typedef long long i64;

// ---------------- twiddle tables: Ct[r,c]=cos(2pi rc/512), St[r,c]=sin(2pi rc/512)
// DFT matrix M = Ct - i*St ; conj(M) = Ct + i*St. Both symmetric.
__global__ __launch_bounds__(256) void k_twiddle(float* __restrict__ Ct,
                                                 float* __restrict__ St) {
    int idx = blockIdx.x * 256 + threadIdx.x;      // 0..262143
    int r = idx >> 9, c = idx & 511;
    int k = (r * c) & 511;
    float ph = (float)k * 0.012271846303085129f;   // 2*pi/512
    float s, co;
    sincosf(ph, &s, &co);
    Ct[idx] = co;
    St[idx] = s;
}

// ---------------- real GEMM: Out[m,t] = sum_k A[m,k]*In[k,t] + bias[m]
// per-slab (blockIdx.z) 512x256 = A(512x512) @ In_slab(512x256). Tile 64x64.
__global__ __launch_bounds__(256) void k_lin(const float* __restrict__ A,
                                             const float* __restrict__ In,
                                             const float* __restrict__ bias,
                                             float* __restrict__ Out) {
    __shared__ float la[16][68];   // A-tile transposed [k][m], +4 pad
    __shared__ float lb[16][68];   // B-tile [k][t]
    const int slab = blockIdx.z;
    const float* Bs = In + (i64)slab * PLANE;
    float* Cs = Out + (i64)slab * PLANE;
    const int t0 = blockIdx.x * 64, m0 = blockIdx.y * 64;
    const int tid = threadIdx.x;
    const int tx = tid & 15, ty = tid >> 4;
    const int ar = tid >> 2, ac = (tid & 3) * 4;   // A staging: row ar, k-cols ac..ac+3
    const int br = tid >> 4, bc = (tid & 15) * 4;  // B staging: k-row br, t-cols bc..bc+3
    float acc[4][4] = {};
    for (int k0 = 0; k0 < FB; k0 += 16) {
        float4 av = *(const float4*)&A[(i64)(m0 + ar) * FB + k0 + ac];
        float4 bv = *(const float4*)&Bs[(i64)(k0 + br) * TB + t0 + bc];
        __syncthreads();
        la[ac + 0][ar] = av.x; la[ac + 1][ar] = av.y;
        la[ac + 2][ar] = av.z; la[ac + 3][ar] = av.w;
        *(float4*)&lb[br][bc] = bv;
        __syncthreads();
#pragma unroll
        for (int kk = 0; kk < 16; ++kk) {
            float4 a4 = *(const float4*)&la[kk][ty * 4];
            float4 b4 = *(const float4*)&lb[kk][tx * 4];
            const float ai[4] = {a4.x, a4.y, a4.z, a4.w};
            const float bj[4] = {b4.x, b4.y, b4.z, b4.w};
#pragma unroll
            for (int i = 0; i < 4; ++i)
#pragma unroll
                for (int j = 0; j < 4; ++j)
                    acc[i][j] = fmaf(ai[i], bj[j], acc[i][j]);
        }
    }
#pragma unroll
    for (int i = 0; i < 4; ++i) {
        float bi = bias[m0 + ty * 4 + i];
        float4 o = make_float4(acc[i][0] + bi, acc[i][1] + bi,
                               acc[i][2] + bi, acc[i][3] + bi);
        *(float4*)&Cs[(i64)(m0 + ty * 4 + i) * TB + t0 + tx * 4] = o;
    }
}

// ---------------- softmax along F (rows) per column t, in place.
// grid (TB/64, 256 slabs), block 256: lane l = t within 64-chunk, part = j-phase.
__global__ __launch_bounds__(256) void k_softmax(float* __restrict__ W) {
    const int slab = blockIdx.y;
    const int l = threadIdx.x & 63;
    const int part = threadIdx.x >> 6;
    const int t = blockIdx.x * 64 + l;
    float* P = W + (i64)slab * PLANE + t;
    __shared__ float red[4][64];
    float mx = -3.0e38f;
    for (int j = part; j < FB; j += 4) mx = fmaxf(mx, P[(i64)j * TB]);
    red[part][l] = mx;
    __syncthreads();
    mx = fmaxf(fmaxf(red[0][l], red[1][l]), fmaxf(red[2][l], red[3][l]));
    __syncthreads();
    float sm = 0.f;
    for (int j = part; j < FB; j += 4) sm += __expf(P[(i64)j * TB] - mx);
    red[part][l] = sm;
    __syncthreads();
    sm = red[0][l] + red[1][l] + red[2][l] + red[3][l];
    float inv = 1.0f / sm;
    for (int j = part; j < FB; j += 4) {
        float v = __expf(P[(i64)j * TB] - mx) * inv;
        P[(i64)j * TB] = v;
    }
}

// ---------------- complex GEMM along F:
// SGN=-1: acc = (Ct + i St) @ Z   (IDFT direction, unscaled)
// SGN=+1: acc = (Ct - i St) @ Z   (DFT direction)
// DOMUL=0: write scale*acc to OutBuf planes.
// DOMUL=1: write (acc * Other) complex product to OutBuf planes (in-place safe).
// In/OutBuf/Other are NTOT-layout tensors; complex slab cs -> re plane b*32+d, im plane b*32+16+d.
template <int SGN, int DOMUL>
__global__ __launch_bounds__(256) void k_cplx(const float* __restrict__ Ct,
                                              const float* __restrict__ St,
                                              const float* __restrict__ In,
                                              float* __restrict__ OutBuf,
                                              const float* __restrict__ Other,
                                              float scale) {
    __shared__ float lc[16][68];
    __shared__ float ls[16][68];
    __shared__ float lr[16][68];
    __shared__ float li[16][68];
    const int cs = blockIdx.z;
    const int b = cs >> 4, d = cs & 15;
    const i64 reoff = (i64)(b * 32 + d) * PLANE;
    const i64 imoff = (i64)(b * 32 + 16 + d) * PLANE;
    const float* Br = In + reoff;
    const float* Bi = In + imoff;
    const int t0 = blockIdx.x * 64, m0 = blockIdx.y * 64;
    const int tid = threadIdx.x;
    const int tx = tid & 15, ty = tid >> 4;
    const int ar = tid >> 2, ac = (tid & 3) * 4;
    const int br = tid >> 4, bc = (tid & 15) * 4;
    float are[4][4] = {};
    float aim[4][4] = {};
    for (int k0 = 0; k0 < FB; k0 += 16) {
        float4 cv = *(const float4*)&Ct[(i64)(m0 + ar) * FB + k0 + ac];
        float4 sv = *(const float4*)&St[(i64)(m0 + ar) * FB + k0 + ac];
        float4 rv = *(const float4*)&Br[(i64)(k0 + br) * TB + t0 + bc];
        float4 iv = *(const float4*)&Bi[(i64)(k0 + br) * TB + t0 + bc];
        __syncthreads();
        lc[ac + 0][ar] = cv.x; lc[ac + 1][ar] = cv.y;
        lc[ac + 2][ar] = cv.z; lc[ac + 3][ar] = cv.w;
        ls[ac + 0][ar] = sv.x; ls[ac + 1][ar] = sv.y;
        ls[ac + 2][ar] = sv.z; ls[ac + 3][ar] = sv.w;
        *(float4*)&lr[br][bc] = rv;
        *(float4*)&li[br][bc] = iv;
        __syncthreads();
#pragma unroll
        for (int kk = 0; kk < 16; ++kk) {
            float4 c4 = *(const float4*)&lc[kk][ty * 4];
            float4 s4 = *(const float4*)&ls[kk][ty * 4];
            float4 r4 = *(const float4*)&lr[kk][tx * 4];
            float4 i4 = *(const float4*)&li[kk][tx * 4];
            const float cc[4] = {c4.x, c4.y, c4.z, c4.w};
            const float ss[4] = {s4.x, s4.y, s4.z, s4.w};
            const float rr[4] = {r4.x, r4.y, r4.z, r4.w};
            const float ii[4] = {i4.x, i4.y, i4.z, i4.w};
#pragma unroll
            for (int i = 0; i < 4; ++i)
#pragma unroll
                for (int j = 0; j < 4; ++j) {
                    are[i][j] = fmaf(cc[i], rr[j], are[i][j]);
                    aim[i][j] = fmaf(cc[i], ii[j], aim[i][j]);
                    if (SGN < 0) {
                        are[i][j] = fmaf(-ss[i], ii[j], are[i][j]);
                        aim[i][j] = fmaf(ss[i], rr[j], aim[i][j]);
                    } else {
                        are[i][j] = fmaf(ss[i], ii[j], are[i][j]);
                        aim[i][j] = fmaf(-ss[i], rr[j], aim[i][j]);
                    }
                }
        }
    }
#pragma unroll
    for (int i = 0; i < 4; ++i) {
        const int m = m0 + ty * 4 + i;
        const i64 row = (i64)m * TB + t0 + tx * 4;
        if (DOMUL) {
            float4 xr = *(const float4*)&Other[reoff + row];
            float4 xi = *(const float4*)&Other[imoff + row];
            const float xrr[4] = {xr.x, xr.y, xr.z, xr.w};
            const float xii[4] = {xi.x, xi.y, xi.z, xi.w};
            float pr[4], pi[4];
#pragma unroll
            for (int j = 0; j < 4; ++j) {
                pr[j] = are[i][j] * xrr[j] - aim[i][j] * xii[j];
                pi[j] = are[i][j] * xii[j] + aim[i][j] * xrr[j];
            }
            *(float4*)&OutBuf[reoff + row] = make_float4(pr[0], pr[1], pr[2], pr[3]);
            *(float4*)&OutBuf[imoff + row] = make_float4(pi[0], pi[1], pi[2], pi[3]);
        } else {
            *(float4*)&OutBuf[reoff + row] =
                make_float4(scale * are[i][0], scale * are[i][1],
                            scale * are[i][2], scale * are[i][3]);
            *(float4*)&OutBuf[imoff + row] =
                make_float4(scale * aim[i][0], scale * aim[i][1],
                            scale * aim[i][2], scale * aim[i][3]);
        }
    }
}

extern "C" void kernel_launch(void* const* d_in, const int* in_sizes, int n_in,
                              void* d_out, int out_size, void* d_ws, size_t ws_size,
                              hipStream_t stream) {
    (void)in_sizes; (void)n_in; (void)out_size; (void)ws_size;
    const float* x  = (const float*)d_in[0];
    const float* W1 = (const float*)d_in[1];
    const float* b1 = (const float*)d_in[2];
    const float* W2 = (const float*)d_in[3];
    const float* b2 = (const float*)d_in[4];
    float* out = (float*)d_out;

    char* ws = (char*)d_ws;
    float* Ct = (float*)ws;
    float* St = (float*)(ws + (i64)FB * FB * 4);
    float* buf1 = (float*)(ws + (i64)2 * FB * FB * 4);   // 134 MB f32 scratch

    // twiddles
    k_twiddle<<<dim3(1024), dim3(256), 0, stream>>>(Ct, St);

    // K1: L1 = W1 @ X + b1  (256 planes, F-major layout so no transposes anywhere)
    dim3 gl(TB / 64, FB / 64, 256);
    k_lin<<<gl, dim3(256), 0, stream>>>(W1, x, b1, buf1);
    // K2: L2 = W2 @ L1 + b2 -> d_out used as scratch (dead before final write)
    k_lin<<<gl, dim3(256), 0, stream>>>(W2, buf1, b2, out);
    // K3: softmax along F, in place -> w
    k_softmax<<<dim3(TB / 64, 256), dim3(256), 0, stream>>>(out);

    dim3 gc(TB / 64, FB / 64, 128);
    // K4a: Xi = (1/F) * conjM @ X      -> buf1  (L1 is dead)
    k_cplx<-1, 0><<<gc, dim3(256), 0, stream>>>(Ct, St, x, buf1, nullptr, 1.0f / 512.0f);
    // K4b: P = (conjM @ w) * Xi        -> buf1 in place (tile-local read/write)
    k_cplx<-1, 1><<<gc, dim3(256), 0, stream>>>(Ct, St, out, buf1, buf1, 1.0f);
    // K5: out = M @ P                  (== h (*) w, the circular convolution)
    k_cplx<+1, 0><<<gc, dim3(256), 0, stream>>>(Ct, St, buf1, out, nullptr, 1.0f);
}

// Round 2
// 460.017 us; speedup vs baseline: 7.0690x; 7.0690x over previous
//
#include <hip/hip_runtime.h>
#include <math.h>

#define FB 512
#define TB 256
#define PLANE (FB * TB)
typedef long long i64;
typedef _Float16 f16;
typedef _Float16 f16x8 __attribute__((ext_vector_type(8)));
typedef _Float16 f16x4 __attribute__((ext_vector_type(4)));
typedef float f32x4 __attribute__((ext_vector_type(4)));
typedef int i32x4 __attribute__((ext_vector_type(4)));

#define MFMA16(a, b, c) __builtin_amdgcn_mfma_f32_16x16x32_f16(a, b, c, 0, 0, 0)

__device__ __forceinline__ f16x8 neg8(f16x8 v) {
    i32x4 u = __builtin_bit_cast(i32x4, v);
    u ^= (int)0x80008000u;
    return __builtin_bit_cast(f16x8, u);
}

// ---------- twiddles in f16: Ct=cos(2pi rc/512), St=sin(2pi rc/512)
__global__ __launch_bounds__(256) void k_twiddle16(f16* __restrict__ Ct,
                                                   f16* __restrict__ St) {
    int idx = blockIdx.x * 256 + threadIdx.x;
    int r = idx >> 9, c = idx & 511;
    int k = (r * c) & 511;
    float ph = (float)k * 0.012271846303085129f;
    float s, co;
    sincosf(ph, &s, &co);
    Ct[idx] = (f16)co;
    St[idx] = (f16)s;
}

// ---------- f32 -> f16 convert (W1, W2), layout preserved
__global__ __launch_bounds__(256) void k_cvtw(const float* __restrict__ W,
                                              f16* __restrict__ O) {
    int idx = (blockIdx.x * 256 + threadIdx.x) * 8;
    float4 a = *(const float4*)&W[idx];
    float4 b = *(const float4*)&W[idx + 4];
    f16x8 o;
    o[0] = (f16)a.x; o[1] = (f16)a.y; o[2] = (f16)a.z; o[3] = (f16)a.w;
    o[4] = (f16)b.x; o[5] = (f16)b.y; o[6] = (f16)b.z; o[7] = (f16)b.w;
    *(f16x8*)&O[idx] = o;
}

// ---------- x f32 [f][t] -> xh f16 transposed [t][f], per plane, via LDS
__global__ __launch_bounds__(256) void k_transpose_cvt(const float* __restrict__ X,
                                                       f16* __restrict__ O) {
    __shared__ float ld[64][65];
    const int p = blockIdx.z;
    const float* src = X + (i64)p * PLANE;
    f16* dst = O + (i64)p * PLANE;
    const int f0 = blockIdx.y * 64, t0 = blockIdx.x * 64;
    const int tid = threadIdx.x;
    const int lrr = tid >> 4, lc = (tid & 15) * 4;
#pragma unroll
    for (int i = 0; i < 4; ++i) {
        float4 v = *(const float4*)&src[(i64)(f0 + lrr + i * 16) * TB + t0 + lc];
        ld[lrr + i * 16][lc + 0] = v.x;
        ld[lrr + i * 16][lc + 1] = v.y;
        ld[lrr + i * 16][lc + 2] = v.z;
        ld[lrr + i * 16][lc + 3] = v.w;
    }
    __syncthreads();
    const int tr = tid >> 2, fq = tid & 3;
#pragma unroll
    for (int i = 0; i < 4; ++i) {
        const int fl = fq * 16 + i * 4;
        f16x4 o;
#pragma unroll
        for (int j = 0; j < 4; ++j) o[j] = (f16)ld[fl + j][tr];
        *(f16x4*)&dst[(i64)(t0 + tr) * FB + f0 + fl] = o;
    }
}

// ---------- real MFMA GEMM: Out[t][m] (f16, transposed) = sum_k A[m][k]*In[t][k] + bias[m]
// In is transposed-f16 [t][f]; A is f16 [m][k]; per-slab blockIdx.z.
__global__ __launch_bounds__(256, 2) void k_rgemm(const f16* __restrict__ A,
                                                  const f16* __restrict__ In,
                                                  const float* __restrict__ bias,
                                                  f16* __restrict__ Out) {
    __shared__ f16 Asx[128][40], Bsx[128][40];
    const int slab = blockIdx.z;
    const f16* Bsrc = In + (i64)slab * PLANE;
    f16* Odst = Out + (i64)slab * PLANE;
    const int t0 = blockIdx.x * 128, m0 = blockIdx.y * 128;
    const int tid = threadIdx.x;
    const int wave = tid >> 6, lane = tid & 63;
    const int wm = wave >> 1, wn = wave & 1;
    const int lr = lane & 15, lg = lane >> 4;
    const int srow = tid >> 2, sgrp = (tid & 3) * 8;

    f32x4 acc[4][4] = {};
    f16x8 nA[2], nB[2];
#pragma unroll
    for (int i = 0; i < 2; ++i) {
        const int row = i * 64 + srow;
        nA[i] = *(const f16x8*)(A + (i64)(m0 + row) * FB + sgrp);
        nB[i] = *(const f16x8*)(Bsrc + (i64)(t0 + row) * FB + sgrp);
    }
#pragma unroll
    for (int i = 0; i < 2; ++i) {
        const int row = i * 64 + srow;
        *(f16x8*)&Asx[row][sgrp] = nA[i];
        *(f16x8*)&Bsx[row][sgrp] = nB[i];
    }
    __syncthreads();

#pragma unroll 1
    for (int kt = 0; kt < 16; ++kt) {
        if (kt < 15) {
            const int k0 = (kt + 1) * 32;
#pragma unroll
            for (int i = 0; i < 2; ++i) {
                const int row = i * 64 + srow;
                nA[i] = *(const f16x8*)(A + (i64)(m0 + row) * FB + k0 + sgrp);
                nB[i] = *(const f16x8*)(Bsrc + (i64)(t0 + row) * FB + k0 + sgrp);
            }
        }
        f16x8 aA[4], bB[4];
#pragma unroll
        for (int mf = 0; mf < 4; ++mf)
            aA[mf] = *(const f16x8*)&Asx[wm * 64 + mf * 16 + lr][lg * 8];
#pragma unroll
        for (int nf = 0; nf < 4; ++nf)
            bB[nf] = *(const f16x8*)&Bsx[wn * 64 + nf * 16 + lr][lg * 8];
#pragma unroll
        for (int nf = 0; nf < 4; ++nf)
#pragma unroll
            for (int mf = 0; mf < 4; ++mf)
                acc[mf][nf] = MFMA16(aA[mf], bB[nf], acc[mf][nf]);
        __syncthreads();
        if (kt < 15) {
#pragma unroll
            for (int i = 0; i < 2; ++i) {
                const int row = i * 64 + srow;
                *(f16x8*)&Asx[row][sgrp] = nA[i];
                *(f16x8*)&Bsx[row][sgrp] = nB[i];
            }
        }
        __syncthreads();
    }

#pragma unroll
    for (int mf = 0; mf < 4; ++mf) {
        const int m = m0 + wm * 64 + mf * 16 + lg * 4;
        const float4 bv = *(const float4*)&bias[m];
        const float bb[4] = {bv.x, bv.y, bv.z, bv.w};
#pragma unroll
        for (int nf = 0; nf < 4; ++nf) {
            const int t = t0 + wn * 64 + nf * 16 + lr;
            f16x4 o;
#pragma unroll
            for (int r = 0; r < 4; ++r) o[r] = (f16)(acc[mf][nf][r] + bb[r]);
            *(f16x4*)&Odst[(i64)t * FB + m] = o;
        }
    }
}

// ---------- row softmax along f (contiguous) on transposed f16 buffer, in place
__global__ __launch_bounds__(256) void k_softmax16(f16* __restrict__ W) {
    const i64 row = (i64)blockIdx.x * 4 + (threadIdx.x >> 6);
    f16* P = W + row * FB + (i64)(threadIdx.x & 63) * 8;
    f16x8 v = *(const f16x8*)P;
    float f[8];
#pragma unroll
    for (int j = 0; j < 8; ++j) f[j] = (float)v[j];
    float mx = f[0];
#pragma unroll
    for (int j = 1; j < 8; ++j) mx = fmaxf(mx, f[j]);
#pragma unroll
    for (int o = 32; o > 0; o >>= 1) mx = fmaxf(mx, __shfl_xor(mx, o));
    float e[8], s = 0.f;
#pragma unroll
    for (int j = 0; j < 8; ++j) { e[j] = __expf(f[j] - mx); s += e[j]; }
#pragma unroll
    for (int o = 32; o > 0; o >>= 1) s += __shfl_xor(s, o);
    const float inv = 1.0f / s;
#pragma unroll
    for (int j = 0; j < 8; ++j) v[j] = (f16)(e[j] * inv);
    *(f16x8*)P = v;
}

// ---------- complex MFMA GEMM along F.
// SGN=-1: acc = (C + iS) @ Z   (IDFT direction, unscaled)
// SGN=+1: acc = (C - iS) @ Z   (DFT direction)
// DOMUL=1: out = acc * Other (complex, elementwise, tile-local in-place safe)
// OUTF32=0: write f16 transposed [t][m] planes; OUTF32=1: write f32 [m][t] planes.
template <int SGN, int DOMUL, int OUTF32>
__global__ __launch_bounds__(256, 2) void k_cgemm(const f16* __restrict__ Cmat,
                                                  const f16* __restrict__ Smat,
                                                  const f16* __restrict__ In,
                                                  void* __restrict__ OutBuf,
                                                  const f16* __restrict__ Other,
                                                  float scale) {
    __shared__ f16 Ac[128][40], Asx[128][40], Brs[128][40], Bis[128][40];
    const int cs = blockIdx.z;
    const int b = cs >> 4, d = cs & 15;
    const i64 reoff = (i64)(b * 32 + d) * PLANE;
    const i64 imoff = (i64)(b * 32 + 16 + d) * PLANE;
    const f16* Bre = In + reoff;
    const f16* Bim = In + imoff;
    const int t0 = blockIdx.x * 128, m0 = blockIdx.y * 128;
    const int tid = threadIdx.x;
    const int wave = tid >> 6, lane = tid & 63;
    const int wm = wave >> 1, wn = wave & 1;
    const int lr = lane & 15, lg = lane >> 4;
    const int srow = tid >> 2, sgrp = (tid & 3) * 8;

    f32x4 accRe[4][4] = {};
    f32x4 accIm[4][4] = {};

    f16x8 nA[4], nB[4];
#pragma unroll
    for (int i = 0; i < 4; ++i) {
        const f16* am = (i >> 1) ? Smat : Cmat;
        const f16* bm = (i >> 1) ? Bim : Bre;
        const int row = (i & 1) * 64 + srow;
        nA[i] = *(const f16x8*)(am + (i64)(m0 + row) * FB + sgrp);
        nB[i] = *(const f16x8*)(bm + (i64)(t0 + row) * FB + sgrp);
    }
#pragma unroll
    for (int i = 0; i < 4; ++i) {
        const int row = (i & 1) * 64 + srow;
        f16(*ad)[40] = (i >> 1) ? Asx : Ac;
        f16(*bd)[40] = (i >> 1) ? Bis : Brs;
        *(f16x8*)&ad[row][sgrp] = nA[i];
        *(f16x8*)&bd[row][sgrp] = nB[i];
    }
    __syncthreads();

#pragma unroll 1
    for (int kt = 0; kt < 16; ++kt) {
        if (kt < 15) {
            const int k0 = (kt + 1) * 32;
#pragma unroll
            for (int i = 0; i < 4; ++i) {
                const f16* am = (i >> 1) ? Smat : Cmat;
                const f16* bm = (i >> 1) ? Bim : Bre;
                const int row = (i & 1) * 64 + srow;
                nA[i] = *(const f16x8*)(am + (i64)(m0 + row) * FB + k0 + sgrp);
                nB[i] = *(const f16x8*)(bm + (i64)(t0 + row) * FB + k0 + sgrp);
            }
        }
        f16x8 aC[4], aS[4], bR[4], bI[4];
#pragma unroll
        for (int mf = 0; mf < 4; ++mf) {
            aC[mf] = *(const f16x8*)&Ac[wm * 64 + mf * 16 + lr][lg * 8];
            aS[mf] = *(const f16x8*)&Asx[wm * 64 + mf * 16 + lr][lg * 8];
        }
#pragma unroll
        for (int nf = 0; nf < 4; ++nf) {
            bR[nf] = *(const f16x8*)&Brs[wn * 64 + nf * 16 + lr][lg * 8];
            bI[nf] = *(const f16x8*)&Bis[wn * 64 + nf * 16 + lr][lg * 8];
        }
#pragma unroll
        for (int nf = 0; nf < 4; ++nf) {
            const f16x8 sIv = (SGN < 0) ? neg8(bI[nf]) : bI[nf];
            const f16x8 sRv = (SGN > 0) ? neg8(bR[nf]) : bR[nf];
#pragma unroll
            for (int mf = 0; mf < 4; ++mf) {
                accRe[mf][nf] = MFMA16(aC[mf], bR[nf], accRe[mf][nf]);
                accRe[mf][nf] = MFMA16(aS[mf], sIv, accRe[mf][nf]);
                accIm[mf][nf] = MFMA16(aC[mf], bI[nf], accIm[mf][nf]);
                accIm[mf][nf] = MFMA16(aS[mf], sRv, accIm[mf][nf]);
            }
        }
        __syncthreads();
        if (kt < 15) {
#pragma unroll
            for (int i = 0; i < 4; ++i) {
                const int row = (i & 1) * 64 + srow;
                f16(*ad)[40] = (i >> 1) ? Asx : Ac;
                f16(*bd)[40] = (i >> 1) ? Bis : Brs;
                *(f16x8*)&ad[row][sgrp] = nA[i];
                *(f16x8*)&bd[row][sgrp] = nB[i];
            }
        }
        __syncthreads();
    }

    if (!OUTF32) {
        f16* Ore = (f16*)OutBuf + reoff;
        f16* Oim = (f16*)OutBuf + imoff;
#pragma unroll
        for (int mf = 0; mf < 4; ++mf) {
            const int m = m0 + wm * 64 + mf * 16 + lg * 4;
#pragma unroll
            for (int nf = 0; nf < 4; ++nf) {
                const int t = t0 + wn * 64 + nf * 16 + lr;
                const i64 off = (i64)t * FB + m;
                f16x4 orr, oii;
                if (DOMUL) {
                    f16x4 xr4 = *(const f16x4*)&Other[reoff + off];
                    f16x4 xi4 = *(const f16x4*)&Other[imoff + off];
#pragma unroll
                    for (int r = 0; r < 4; ++r) {
                        const float ar = accRe[mf][nf][r], ai = accIm[mf][nf][r];
                        const float xr = (float)xr4[r], xi = (float)xi4[r];
                        orr[r] = (f16)(ar * xr - ai * xi);
                        oii[r] = (f16)(ar * xi + ai * xr);
                    }
                } else {
#pragma unroll
                    for (int r = 0; r < 4; ++r) {
                        orr[r] = (f16)(accRe[mf][nf][r] * scale);
                        oii[r] = (f16)(accIm[mf][nf][r] * scale);
                    }
                }
                *(f16x4*)&Ore[off] = orr;
                *(f16x4*)&Oim[off] = oii;
            }
        }
    } else {
        float* O = (float*)OutBuf;
#pragma unroll
        for (int mf = 0; mf < 4; ++mf) {
            const int m = m0 + wm * 64 + mf * 16 + lg * 4;
#pragma unroll
            for (int nf = 0; nf < 4; ++nf) {
                const int t = t0 + wn * 64 + nf * 16 + lr;
#pragma unroll
                for (int r = 0; r < 4; ++r) {
                    O[reoff + (i64)(m + r) * TB + t] = accRe[mf][nf][r] * scale;
                    O[imoff + (i64)(m + r) * TB + t] = accIm[mf][nf][r] * scale;
                }
            }
        }
    }
}

extern "C" void kernel_launch(void* const* d_in, const int* in_sizes, int n_in,
                              void* d_out, int out_size, void* d_ws, size_t ws_size,
                              hipStream_t stream) {
    (void)in_sizes; (void)n_in; (void)out_size; (void)ws_size;
    const float* x = (const float*)d_in[0];
    const float* W1 = (const float*)d_in[1];
    const float* b1 = (const float*)d_in[2];
    const float* W2 = (const float*)d_in[3];
    const float* b2 = (const float*)d_in[4];
    float* out = (float*)d_out;

    char* ws = (char*)d_ws;
    const i64 MATB = (i64)FB * FB * 2;          // 512 KB per f16 512x512 matrix
    const i64 TENB = (i64)256 * PLANE * 2;      // 33.55 MB per f16 tensor
    f16* CtH = (f16*)(ws);
    f16* StH = (f16*)(ws + MATB);
    f16* W1h = (f16*)(ws + 2 * MATB);
    f16* W2h = (f16*)(ws + 3 * MATB);
    f16* xh  = (f16*)(ws + 4 * MATB);
    f16* bufA = (f16*)(ws + 4 * MATB + TENB);
    f16* bufB = (f16*)(ws + 4 * MATB + 2 * TENB);

    // prologue: tables + conversions
    k_twiddle16<<<dim3(1024), dim3(256), 0, stream>>>(CtH, StH);
    k_cvtw<<<dim3(128), dim3(256), 0, stream>>>(W1, W1h);
    k_cvtw<<<dim3(128), dim3(256), 0, stream>>>(W2, W2h);
    k_transpose_cvt<<<dim3(4, 8, 256), dim3(256), 0, stream>>>(x, xh);

    // K1: h1 = W1 @ X + b1      -> bufA (f16, [t][f])
    dim3 gr(TB / 128, FB / 128, 256);
    k_rgemm<<<gr, dim3(256), 0, stream>>>(W1h, xh, b1, bufA);
    // K2: logits = W2 @ h1 + b2 -> bufB
    k_rgemm<<<gr, dim3(256), 0, stream>>>(W2h, bufA, b2, bufB);
    // K3: softmax along f (contiguous rows), in place -> w
    k_softmax16<<<dim3(16384), dim3(256), 0, stream>>>(bufB);

    dim3 gc(TB / 128, FB / 128, 128);
    // K4a: Xi = (1/F)(C+iS) @ X   -> bufA (h1 dead)
    k_cgemm<-1, 0, 0><<<gc, dim3(256), 0, stream>>>(CtH, StH, xh, bufA, nullptr, 1.0f / 512.0f);
    // K4b: P = ((C+iS) @ w) * Xi  -> bufA in place (tile-local)
    k_cgemm<-1, 1, 0><<<gc, dim3(256), 0, stream>>>(CtH, StH, bufB, bufA, bufA, 1.0f);
    // K5: out = (C-iS) @ P        -> d_out f32 [f][t]
    k_cgemm<+1, 0, 1><<<gc, dim3(256), 0, stream>>>(CtH, StH, bufA, out, nullptr, 1.0f);
}